// Round 4
// baseline (1104.516 us; speedup 1.0000x reference)
//
#include <hip/hip_runtime.h>

#define K_DIM 4096
#define N_DIM 11008
#define M_DIM 8192
#define NT 64  // K / 64

typedef _Float16 f16;
typedef f16 f16x4 __attribute__((ext_vector_type(4)));
typedef f16 f16x8 __attribute__((ext_vector_type(8)));
typedef float f32x4 __attribute__((ext_vector_type(4)));

typedef __attribute__((address_space(1))) unsigned int gu32;
typedef __attribute__((address_space(3))) unsigned int lu32;

__device__ __forceinline__ void g2l16(const void* gp, void* lp) {
    __builtin_amdgcn_global_load_lds((gu32*)gp, (lu32*)lp, 16, 0, 0);
}

// ---------------------------------------------------------------------------
// Prepass 1: W int32 -> f16 (int8 values are exact in f16)
// ---------------------------------------------------------------------------
__global__ __launch_bounds__(256) void convw_kernel(const int* __restrict__ Wq,
                                                    f16* __restrict__ Wh) {
    const size_t n4 = (size_t)N_DIM * K_DIM / 4;
    const size_t stride = (size_t)gridDim.x * 256;
    const int4* src = (const int4*)Wq;
    f16x4* dst = (f16x4*)Wh;
    for (size_t i = (size_t)blockIdx.x * 256 + threadIdx.x; i < n4; i += stride) {
        int4 a = src[i];
        f16x4 o = {(f16)a.x, (f16)a.y, (f16)a.z, (f16)a.w};
        dst[i] = o;
    }
}

// ---------------------------------------------------------------------------
// Prepass 2: X f32 -> f16 + rowsum of converted values
// ---------------------------------------------------------------------------
__global__ __launch_bounds__(256) void convx_kernel(const float* __restrict__ X,
                                                    f16* __restrict__ Xh,
                                                    float* __restrict__ rs) {
    const int row = blockIdx.x;
    const int t = threadIdx.x;
    const float4* xr = (const float4*)(X + (size_t)row * K_DIM);
    f16x4* xo = (f16x4*)(Xh + (size_t)row * K_DIM);
    float s = 0.f;
#pragma unroll
    for (int j = 0; j < 4; ++j) {
        float4 v = xr[t + 256 * j];
        f16x4 h = {(f16)v.x, (f16)v.y, (f16)v.z, (f16)v.w};
        xo[t + 256 * j] = h;
        s += (float)h[0] + (float)h[1] + (float)h[2] + (float)h[3];
    }
#pragma unroll
    for (int off = 32; off > 0; off >>= 1) s += __shfl_down(s, off);
    __shared__ float part[4];
    if ((t & 63) == 0) part[t >> 6] = s;
    __syncthreads();
    if (t == 0) rs[row] = part[0] + part[1] + part[2] + part[3];
}

// ---------------------------------------------------------------------------
// GEMM: 256x256 tile, BK=64, 8 waves (2Mx4N). R4: TWO compartments per
// K-tile (was 4). Shifted pipeline: each compartment's MFMAs consume
// fragments read in the previous compartment; its own ds_reads/stages
// overlap the MFMAs (separate pipes).
//   C0(T): MFMA Q0 (aLo x b01) + Q1 (aLo x b23) || read aHi(T) ||
//          stage B(T+2) -> buf cur;  end: vmcnt(4), lgkmcnt(0), barrier
//   C1(T): MFMA Q2 (aHi x b23) + Q3 (aHi x b01) || read aLo/b01/b23(T+1)
//          from buf cur^1 || stage A(T+2) -> buf cur;  end: lgkmcnt(0), bar
// Liveness: A region fully read after C0(T) (aLo in C1(T-1), aHi in C0(T))
// -> restage A in C1(T). B region fully read after C1(T-1) -> restage B in
// C0(T). Issue order ... A(T+1)[C1(T-1)], B(T+2)[C0(T)], A(T+2)[C1(T)] ...
// so vmcnt(4) at C0(T)-end leaves exactly B(T+2) in flight => all 8 chunks
// of T+1 have landed before C1(T) reads them.
// b01/b23 are register-double-buffered (consumed in C0+C1 while next tile's
// copies load in C1); aLo/aHi single-buffered (reload after last use).
// ---------------------------------------------------------------------------
__global__ __launch_bounds__(512, 2)
void qlin_gemm(const f16* __restrict__ Xh, const f16* __restrict__ Wh,
               const float* __restrict__ scale, const float* __restrict__ zp,
               const float* __restrict__ bias, const float* __restrict__ rowsum,
               float* __restrict__ out) {
    extern __shared__ __align__(16) char smem[];

    const int t = threadIdx.x;
    const int l = t & 63;
    const int w = t >> 6;
    const int wm = w >> 2;  // 0..1 -> rows wm*128
    const int wn = w & 3;   // 0..3 -> cols wn*64
    const int q = l >> 4;
    const int ln = l & 15;

    const int m0 = blockIdx.x * 256;  // m-fastest dispatch (R1 win)
    const int n0 = blockIdx.y * 256;

    // staging: thread t handles local row t>>3 of a 64-row chunk, phys slot t&7
    const int srow = t >> 3;
    const int sslot = (t & 7) ^ (srow & 7);
    const char* xbase = (const char*)Xh + ((size_t)(m0 + srow) << 13) + (sslot << 4);
    const char* wbase = (const char*)Wh + ((size_t)(n0 + srow) << 13) + (sslot << 4);
    char* ldst = smem + t * 16;

#define STG_A(p, c, T) g2l16(xbase + ((size_t)(c) << 19) + ((size_t)(T) << 7), ldst + (p)*65536 + (c)*8192)
#define STG_B(p, c, T) g2l16(wbase + ((size_t)(c) << 19) + ((size_t)(T) << 7), ldst + (p)*65536 + 32768 + (c)*8192)
#define SB __builtin_amdgcn_sched_barrier(0)
#define BAR __builtin_amdgcn_s_barrier()
#define LGKM0 asm volatile("s_waitcnt lgkmcnt(0)" ::: "memory")
#define VMC4 asm volatile("s_waitcnt vmcnt(4)" ::: "memory")

    // ds_read lane offsets: row = base + frag*16 + ln, phys slot = (q+kk*4) ^ (ln&7)
    const int xs = ln & 7;
    int offA[2], offB[2];
    offA[0] = (wm * 128 + ln) * 128 + ((q ^ xs) << 4);
    offA[1] = (wm * 128 + ln) * 128 + (((q + 4) ^ xs) << 4);
    offB[0] = 32768 + (wn * 64 + ln) * 128 + ((q ^ xs) << 4);
    offB[1] = 32768 + (wn * 64 + ln) * 128 + (((q + 4) ^ xs) << 4);

    f32x4 acc[8][4] = {};
    f16x8 aL[4][2], aH[4][2];
    f16x8 b01A[2][2], b23A[2][2], b01B[2][2], b23B[2][2];

#define RD_AL(P)                                                               \
    _Pragma("unroll") for (int kk = 0; kk < 2; ++kk)                           \
    _Pragma("unroll") for (int i = 0; i < 4; ++i)                              \
        aL[i][kk] = *(const f16x8*)(smem + (P)*65536 + offA[kk] + i * 2048)
#define RD_AH(P)                                                               \
    _Pragma("unroll") for (int kk = 0; kk < 2; ++kk)                           \
    _Pragma("unroll") for (int i = 0; i < 4; ++i)                              \
        aH[i][kk] = *(const f16x8*)(smem + (P)*65536 + offA[kk] + (4 + i) * 2048)
#define RD_B01(P, D)                                                           \
    _Pragma("unroll") for (int kk = 0; kk < 2; ++kk)                           \
    _Pragma("unroll") for (int j = 0; j < 2; ++j)                              \
        D[j][kk] = *(const f16x8*)(smem + (P)*65536 + offB[kk] + j * 2048)
#define RD_B23(P, D)                                                           \
    _Pragma("unroll") for (int kk = 0; kk < 2; ++kk)                           \
    _Pragma("unroll") for (int j = 0; j < 2; ++j)                              \
        D[j][kk] = *(const f16x8*)(smem + (P)*65536 + offB[kk] + (2 + j) * 2048)
#define MFMA_BLK(I0, J0, ASET, BSET)                                           \
    _Pragma("unroll") for (int kk = 0; kk < 2; ++kk)                           \
    _Pragma("unroll") for (int i = 0; i < 4; ++i)                              \
    _Pragma("unroll") for (int j = 0; j < 2; ++j)                              \
        acc[(I0) + i][(J0) + j] = __builtin_amdgcn_mfma_f32_16x16x32_f16(      \
            ASET[i][kk], BSET[j][kk], acc[(I0) + i][(J0) + j], 0, 0, 0)

    // ---- prologue: B(0),A(0)->buf0; B(1)->buf1; vmcnt(4): T0 landed ----
    STG_B(0, 0, 0); STG_B(0, 1, 0); STG_B(0, 2, 0); STG_B(0, 3, 0);
    STG_A(0, 0, 0); STG_A(0, 1, 0); STG_A(0, 2, 0); STG_A(0, 3, 0);
    STG_B(1, 0, 1); STG_B(1, 1, 1); STG_B(1, 2, 1); STG_B(1, 3, 1);
    VMC4; SB; BAR; SB;
    // pre-compartment (== C1 of virtual tile -1): read T0 frags; stage A(1)
    RD_AL(0); RD_B01(0, b01A); RD_B23(0, b23A);
    STG_A(1, 0, 1); STG_A(1, 1, 1); STG_A(1, 2, 1); STG_A(1, 3, 1);
    LGKM0; SB; BAR; SB;

#define BODY(T, CUR, BS, BD)                                                   \
    /* C0: MFMA Q0,Q1 || read aHi(T) || stage B(T+2) */                        \
    RD_AH(CUR);                                                                \
    MFMA_BLK(0, 0, aL, b01##BS);                                               \
    MFMA_BLK(0, 2, aL, b23##BS);                                               \
    STG_B(CUR, 0, (T) + 2); STG_B(CUR, 1, (T) + 2);                            \
    STG_B(CUR, 2, (T) + 2); STG_B(CUR, 3, (T) + 2);                            \
    VMC4; LGKM0; SB; BAR; SB;                                                  \
    /* C1: MFMA Q2,Q3 || read aLo/b01/b23(T+1) from buf^1 || stage A(T+2) */   \
    RD_AL((CUR) ^ 1); RD_B01((CUR) ^ 1, b01##BD); RD_B23((CUR) ^ 1, b23##BD);  \
    MFMA_BLK(4, 2, aH, b23##BS);                                               \
    MFMA_BLK(4, 0, aH, b01##BS);                                               \
    STG_A(CUR, 0, (T) + 2); STG_A(CUR, 1, (T) + 2);                            \
    STG_A(CUR, 2, (T) + 2); STG_A(CUR, 3, (T) + 2);                            \
    LGKM0; SB; BAR; SB;

    // main loop: tiles 0..61 (stage targets T+2 <= 63 always valid)
#pragma unroll 1
    for (int Tp = 0; Tp < 31; ++Tp) {
        BODY(2 * Tp, 0, A, B);
        BODY(2 * Tp + 1, 1, B, A);
    }
#undef BODY

    // ---- tail: tile 62 (buf0, consume set A; no more stages) ----
    RD_AH(0);
    MFMA_BLK(0, 0, aL, b01A);
    MFMA_BLK(0, 2, aL, b23A);
    // A(63) (issued in C1(61)) must land before reading buf1
    asm volatile("s_waitcnt vmcnt(0)" ::: "memory");
    LGKM0; SB; BAR; SB;
    RD_AL(1); RD_B01(1, b01B); RD_B23(1, b23B);
    MFMA_BLK(4, 2, aH, b23A);
    MFMA_BLK(4, 0, aH, b01A);
    // ---- tail: tile 63 (buf1, register-only ordering; no barriers) ----
    RD_AH(1);
    MFMA_BLK(0, 0, aL, b01B);
    MFMA_BLK(0, 2, aL, b23B);
    MFMA_BLK(4, 2, aH, b23B);
    MFMA_BLK(4, 0, aH, b01B);

    // epilogue: y[m,n] = scale[n]*(dot - zp[n]*rowsum[m]) + bias[n]
    float sc[4], zv[4], bv[4];
    int ncol[4];
#pragma unroll
    for (int j = 0; j < 4; ++j) {
        const int n = n0 + wn * 64 + j * 16 + ln;
        ncol[j] = n;
        sc[j] = scale[n];
        zv[j] = zp[n];
        bv[j] = bias[n];
    }
#pragma unroll
    for (int i = 0; i < 8; ++i) {
#pragma unroll
        for (int r = 0; r < 4; ++r) {
            const int m = m0 + wm * 128 + i * 16 + q * 4 + r;
            const float rsm = rowsum[m];
            const size_t rowoff = (size_t)m * N_DIM;
#pragma unroll
            for (int j = 0; j < 4; ++j) {
                out[rowoff + ncol[j]] = sc[j] * (acc[i][j][r] - zv[j] * rsm) + bv[j];
            }
        }
    }
}

extern "C" void kernel_launch(void* const* d_in, const int* in_sizes, int n_in,
                              void* d_out, int out_size, void* d_ws, size_t ws_size,
                              hipStream_t stream) {
    const float* X     = (const float*)d_in[0];
    const int*   Wq    = (const int*)d_in[1];
    const float* scale = (const float*)d_in[2];
    const float* zp    = (const float*)d_in[3];
    const float* bias  = (const float*)d_in[4];
    float* out = (float*)d_out;

    // ws layout: Wh (90,177,536 B) | Xh (67,108,864 B) | rowsum (32 KB)
    f16* Wh = (f16*)d_ws;
    f16* Xh = (f16*)((char*)d_ws + (size_t)N_DIM * K_DIM * 2);
    float* rowsum = (float*)((char*)d_ws + (size_t)N_DIM * K_DIM * 2 + (size_t)M_DIM * K_DIM * 2);

    static bool attr_done = false;
    if (!attr_done) {
        (void)hipFuncSetAttribute((const void*)qlin_gemm,
                                  hipFuncAttributeMaxDynamicSharedMemorySize, 131072);
        attr_done = true;
    }

    convw_kernel<<<4096, 256, 0, stream>>>(Wq, Wh);
    convx_kernel<<<M_DIM, 256, 0, stream>>>(X, Xh, rowsum);

    dim3 grid(M_DIM / 256, N_DIM / 256);  // (32, 43): m-fastest for W stream-once
    qlin_gemm<<<grid, 512, 131072, stream>>>(Xh, Wh, scale, zp, bias, rowsum, out);
}